// Round 6
// baseline (231.822 us; speedup 1.0000x reference)
//
#include <hip/hip_runtime.h>

#define L_SEQ 1024
#define EMB 1024
#define NH 16
#define HD 64

typedef _Float16 half8 __attribute__((ext_vector_type(8)));
typedef _Float16 half4v __attribute__((ext_vector_type(4)));
typedef __fp16 h2 __attribute__((ext_vector_type(2)));
typedef float f32x4 __attribute__((ext_vector_type(4)));
typedef float f32x16 __attribute__((ext_vector_type(16)));
typedef float fvec4 __attribute__((ext_vector_type(4)));
typedef unsigned int u32;
typedef u32 u32x4 __attribute__((ext_vector_type(4)));
typedef unsigned long long u64;

constexpr float C2 = 0.045084220027780106f;   // SCALE * log2(e) -- folded into K16 prepass

constexpr int PP = 66;   // cvt_kv LDS pitch (132B rows: write banks 16-spread vs 8 @144B)

__device__ __forceinline__ void async16(const void* g, void* l) {
    __builtin_amdgcn_global_load_lds((const __attribute__((address_space(1))) u32*)g,
                                     (__attribute__((address_space(3))) u32*)l, 16, 0, 0);
}

// ---------------------------------------------------------------------------
// Prepass (merged): pack attn_mask bits; blocks<32 pack pad mask;
// blocks<1024 also convert fc_w fp32->f16. One launch instead of two.
// ---------------------------------------------------------------------------
__global__ void prep_kernel(const int* __restrict__ am, u32* __restrict__ bits,
                            const int* __restrict__ pad, u32* __restrict__ pbits,
                            const float* __restrict__ w, _Float16* __restrict__ o) {
    const int b = blockIdx.x;
    const int i = b * 256 + threadIdx.x;
    const int lane = threadIdx.x & 63;
    u64 bal = __ballot(am[i] != 0);
    if (lane == 0)       bits[i >> 5] = (u32)bal;
    else if (lane == 32) bits[i >> 5] = (u32)(bal >> 32);
    if (b < 32) {   // 8*1024 pad ints
        u64 pb = __ballot(pad[i] != 0);
        if (lane == 0)       pbits[i >> 5] = (u32)pb;
        else if (lane == 32) pbits[i >> 5] = (u32)(pb >> 32);
    }
    if (b < 1024) {   // fc_w convert: 1M floats
        size_t j = (size_t)i * 4;
        fvec4 v = *(const fvec4*)(w + j);
        half4v hh;
#pragma unroll
        for (int k = 0; k < 4; ++k) hh[k] = (_Float16)v[k];
        *(half4v*)(o + j) = hh;
    }
}

// ---------------------------------------------------------------------------
// Prepass: K -> f16 head-blocked (nh, k, d) scaled by C2; V -> f16 transposed
// ---------------------------------------------------------------------------
__global__ __launch_bounds__(256) void cvt_kv_kernel(
    const float* __restrict__ keys, const float* __restrict__ values,
    _Float16* __restrict__ K16, _Float16* __restrict__ Vt16)
{
    __shared__ __align__(16) _Float16 Vt[64 * PP];
    const int tid = threadIdx.x;
    const int kt = blockIdx.x, h = blockIdx.y, n = blockIdx.z;
    const int kbase = kt * 64;
    const int r = tid >> 2, c0 = (tid & 3) * 16;
    const int nh = n * NH + h;

    {   // K: reorder rows into head-blocked, convert, fold C2
        const float* src = keys + ((size_t)(n * L_SEQ + kbase + r)) * EMB + h * HD + c0;
        fvec4 a0 = *(const fvec4*)(src),     a1 = *(const fvec4*)(src + 4);
        fvec4 a2 = *(const fvec4*)(src + 8), a3 = *(const fvec4*)(src + 12);
        half8 o0, o1;
#pragma unroll
        for (int j = 0; j < 4; ++j) {
            o0[j] = (_Float16)(a0[j] * C2); o0[j + 4] = (_Float16)(a1[j] * C2);
            o1[j] = (_Float16)(a2[j] * C2); o1[j + 4] = (_Float16)(a3[j] * C2);
        }
        _Float16* dst = K16 + ((size_t)nh * L_SEQ + kbase + r) * HD + c0;
        *(half8*)dst = o0; *(half8*)(dst + 8) = o1;
    }
    {   // V: stage transposed tile in LDS (pitch 66: banks (c0+i)%32 + r/2)
        const float* src = values + ((size_t)(n * L_SEQ + kbase + r)) * EMB + h * HD + c0;
        fvec4 vv[4];
        vv[0] = *(const fvec4*)(src);     vv[1] = *(const fvec4*)(src + 4);
        vv[2] = *(const fvec4*)(src + 8); vv[3] = *(const fvec4*)(src + 12);
#pragma unroll
        for (int i = 0; i < 16; ++i)
            Vt[(c0 + i) * PP + r] = (_Float16)vv[i >> 2][i & 3];
    }
    __syncthreads();
    {   // write Vt16 rows (d-major); 132B rows are 4B-aligned -> u32 LDS reads
        const int d = tid >> 2, k0 = (tid & 3) * 16;
        const u32* vr = (const u32*)((const char*)Vt + (size_t)d * (PP * 2) + 2 * k0);
        u32 a[8];
#pragma unroll
        for (int m = 0; m < 8; ++m) a[m] = vr[m];
        u32x4 lo = {a[0], a[1], a[2], a[3]};
        u32x4 hi2 = {a[4], a[5], a[6], a[7]};
        _Float16* dst = Vt16 + ((size_t)nh * HD + d) * L_SEQ + kbase + k0;
        *(half8*)dst = __builtin_bit_cast(half8, lo);
        *(half8*)(dst + 8) = __builtin_bit_cast(half8, hi2);
    }
}

// ---------------------------------------------------------------------------
// Fused masked attention, S^T formulation on 32x32x16 MFMA, in-register
// softmax->PV (permlane32_swap). All in-loop VMEM loads are for tile kt+1
// (no mid-iteration vmcnt wait). ROUND-6: launch_bounds (256,4): 4 blocks/CU
// x 256 CU == grid 1024 exactly -> zero tail, 4 waves/SIMD latency hiding.
// ---------------------------------------------------------------------------
__global__ __launch_bounds__(256, 4) void attn_kernel(
    const _Float16* __restrict__ K16, const _Float16* __restrict__ Vt16,
    const float* __restrict__ queries, const u32* __restrict__ mbits,
    const u32* __restrict__ pbits, _Float16* __restrict__ out_f16)
{
    __shared__ __align__(16) _Float16 K_lds[2][64 * 64];   // XOR-swizzled, double-buffered
    __shared__ __align__(16) _Float16 V_lds[2][64 * 64];   // V^T tile, XOR-swizzled, dbuf
    __shared__ __align__(8)  u32 mtab[32];                 // 4 mask bits -> packed f16 {0,1}x4

    const int tid  = threadIdx.x;
    const int lane = tid & 63;
    const int wv   = tid >> 6;
    const int l32  = lane & 31;
    const int hi   = lane >> 5;
    const int bid  = blockIdx.x;
    const int nh = bid & 127, qt = bid >> 7;
    const int n = nh >> 4, h = nh & 15;
    const int qbase = qt * 128;
    const int q = qbase + wv * 32 + l32;     // this lane's q (S^T column)
    const int rsw = l32 & 7;

    const _Float16* Kt_base = K16 + (size_t)nh * L_SEQ * HD;
    const _Float16* Vt_base = Vt16 + (size_t)nh * HD * L_SEQ;
    const int gch = (lane & 7) ^ ((lane >> 3) & 7);      // XOR-swizzled source chunk

    auto stage = [&](int buf, int kt) {
        const int kbase = kt * 64;
#pragma unroll
        for (int s2 = 0; s2 < 2; ++s2) {
            const int row = wv * 16 + s2 * 8 + (lane >> 3);
            async16(Kt_base + (size_t)(kbase + row) * HD + gch * 8,
                    &K_lds[buf][(wv * 16 + s2 * 8) * 64]);
            async16(Vt_base + (size_t)row * L_SEQ + kbase + gch * 8,
                    &V_lds[buf][(wv * 16 + s2 * 8) * 64]);
        }
    };

    // prologue: tile-0 masks + DMA issued before Q setup (drained by 1st barrier)
    uint2 wm_cur = *(const uint2*)(&mbits[(size_t)q * 32]);
    u32 pl_cur = pbits[n << 5];
    u32 ph_cur = pbits[(n << 5) + 1];
    stage(0, 0);

    if (tid < 16) {
        mtab[tid * 2]     = ((tid & 1) ? 0x3C00u : 0u) | ((tid & 2) ? 0x3C000000u : 0u);
        mtab[tid * 2 + 1] = ((tid & 4) ? 0x3C00u : 0u) | ((tid & 8) ? 0x3C000000u : 0u);
    }

    // --- Q fragments (B operand for S^T): lane holds Q[q][d = c*16 + hi*8 + j]
    half8 qf[4];
    {
        const float* qp = queries + ((size_t)(n * L_SEQ + q)) * EMB + h * HD;
#pragma unroll
        for (int c = 0; c < 4; ++c) {
            fvec4 a = *(const fvec4*)(qp + c * 16 + hi * 8);
            fvec4 b = *(const fvec4*)(qp + c * 16 + hi * 8 + 4);
#pragma unroll
            for (int j = 0; j < 4; ++j) { qf[c][j] = (_Float16)a[j]; qf[c][j + 4] = (_Float16)b[j]; }
        }
    }

    f32x16 Ov[2];
#pragma unroll
    for (int dt = 0; dt < 2; ++dt)
#pragma unroll
        for (int r = 0; r < 16; ++r) Ov[dt][r] = 0.f;
    float lsum = 0.f;
    const h2 one2 = {(__fp16)1.f, (__fp16)1.f};

    int cur = 0;
#pragma unroll 2
    for (int kt = 0; kt < L_SEQ / 64; ++kt) {
        __syncthreads();     // tile kt DMA + kt masks landed; prior-iter LDS reads consumed

        // issue tile kt+1 loads: masks FIRST, then DMA; nothing here is read
        // this iteration, so no vmcnt wait occurs inside the compute phase.
        uint2 wm_next = {0u, 0u};
        u32 pl_next = 0u, ph_next = 0u;
        if (kt + 1 < L_SEQ / 64) {
            wm_next = *(const uint2*)(&mbits[(size_t)q * 32 + (kt + 1) * 2]);
            pl_next = pbits[(n << 5) + ((kt + 1) << 1)];
            ph_next = pbits[(n << 5) + ((kt + 1) << 1) + 1];
            stage(cur ^ 1, kt + 1);
        }

        u32 w[2];
        w[0] = wm_cur.x & pl_cur;
        w[1] = wm_cur.y & ph_cur;

        // --- S^T = K * Q^T  (two 32x32 k-subtiles; C2 pre-folded into K16)
        f32x16 St[2];
#pragma unroll
        for (int i = 0; i < 2; ++i)
#pragma unroll
            for (int r = 0; r < 16; ++r) St[i][r] = 0.f;

        const _Float16* kb = &K_lds[cur][0];
        __builtin_amdgcn_s_setprio(1);
#pragma unroll
        for (int c = 0; c < 4; ++c) {
            const int ch = ((2 * c + hi) ^ rsw) * 8;
            half8 kf0 = *(const half8*)(kb + l32 * 64 + ch);
            half8 kf1 = *(const half8*)(kb + (32 + l32) * 64 + ch);
            St[0] = __builtin_amdgcn_mfma_f32_32x32x16_f16(kf0, qf[c], St[0], 0, 0, 0);
            St[1] = __builtin_amdgcn_mfma_f32_32x32x16_f16(kf1, qf[c], St[1], 0, 0, 0);
        }
        __builtin_amdgcn_s_setprio(0);

        // --- p = exp2(S) * m; pack to f16 pairs; permlane32_swap -> PV A-frags.
        //     St[i][reg] is k_rel = (reg&3)+8*(reg>>2)+4*hi (k = 32i + k_rel).
        u32 pa[4][4];   // [ks][word j' = 2*hi' + mp]
#pragma unroll
        for (int i = 0; i < 2; ++i) {
#pragma unroll
            for (int rgp = 0; rgp < 2; ++rgp) {
                const int rg_a = 2 * rgp, rg_b = 2 * rgp + 1;
                const u32 m4a = (w[i] >> (8 * rg_a + 4 * hi)) & 15u;
                const u32 m4b = (w[i] >> (8 * rg_b + 4 * hi)) & 15u;
                const uint2 mma = *(const uint2*)(&mtab[m4a * 2]);
                const uint2 mmb = *(const uint2*)(&mtab[m4b * 2]);
                const float pa0 = __builtin_amdgcn_exp2f(St[i][4 * rg_a + 0]);
                const float pa1 = __builtin_amdgcn_exp2f(St[i][4 * rg_a + 1]);
                const float pa2 = __builtin_amdgcn_exp2f(St[i][4 * rg_a + 2]);
                const float pa3 = __builtin_amdgcn_exp2f(St[i][4 * rg_a + 3]);
                const float pb0 = __builtin_amdgcn_exp2f(St[i][4 * rg_b + 0]);
                const float pb1 = __builtin_amdgcn_exp2f(St[i][4 * rg_b + 1]);
                const float pb2 = __builtin_amdgcn_exp2f(St[i][4 * rg_b + 2]);
                const float pb3 = __builtin_amdgcn_exp2f(St[i][4 * rg_b + 3]);
                const h2 a0 = __builtin_amdgcn_cvt_pkrtz(pa0, pa1) * __builtin_bit_cast(h2, mma.x);
                const h2 a1 = __builtin_amdgcn_cvt_pkrtz(pa2, pa3) * __builtin_bit_cast(h2, mma.y);
                const h2 b0 = __builtin_amdgcn_cvt_pkrtz(pb0, pb1) * __builtin_bit_cast(h2, mmb.x);
                const h2 b1 = __builtin_amdgcn_cvt_pkrtz(pb2, pb3) * __builtin_bit_cast(h2, mmb.y);
                lsum = __builtin_amdgcn_fdot2(a0, one2, lsum, false);
                lsum = __builtin_amdgcn_fdot2(a1, one2, lsum, false);
                lsum = __builtin_amdgcn_fdot2(b0, one2, lsum, false);
                lsum = __builtin_amdgcn_fdot2(b1, one2, lsum, false);
                u32 A0 = __builtin_bit_cast(u32, a0), A1 = __builtin_bit_cast(u32, a1);
                u32 B0 = __builtin_bit_cast(u32, b0), B1 = __builtin_bit_cast(u32, b1);
                // after swap: A' = {A.lo, B.lo} (j'=mp), B' = {A.hi, B.hi} (j'=2+mp)
                asm("v_permlane32_swap_b32 %0, %1" : "+v"(A0), "+v"(B0));
                asm("v_permlane32_swap_b32 %0, %1" : "+v"(A1), "+v"(B1));
                const int ks = i * 2 + rgp;
                pa[ks][0] = A0; pa[ks][1] = A1; pa[ks][2] = B0; pa[ks][3] = B1;
            }
        }

        // --- O += P * V  (A = P frag from swaps, B = V^T rows)
        const _Float16* vb = &V_lds[cur][0];
        __builtin_amdgcn_s_setprio(1);
#pragma unroll
        for (int ks = 0; ks < 4; ++ks) {
            u32x4 pw = {pa[ks][0], pa[ks][1], pa[ks][2], pa[ks][3]};
            half8 pB = __builtin_bit_cast(half8, pw);
            const int ch = ((2 * ks + hi) ^ rsw) * 8;
            half8 vf0 = *(const half8*)(vb + l32 * 64 + ch);
            half8 vf1 = *(const half8*)(vb + (32 + l32) * 64 + ch);
            Ov[0] = __builtin_amdgcn_mfma_f32_32x32x16_f16(pB, vf0, Ov[0], 0, 0, 0);
            Ov[1] = __builtin_amdgcn_mfma_f32_32x32x16_f16(pB, vf1, Ov[1], 0, 0, 0);
        }
        __builtin_amdgcn_s_setprio(0);

        wm_cur = wm_next; pl_cur = pl_next; ph_cur = ph_next;
        cur ^= 1;
    }

    // --- epilogue: complete row sums (lanes l, l^32 hold same q), normalize, store
    lsum += __shfl_xor(lsum, 32);
    float linv[16];
#pragma unroll
    for (int reg = 0; reg < 16; ++reg) {
        const int qrel = (reg & 3) + 8 * (reg >> 2) + 4 * hi;
        linv[reg] = 1.0f / fmaxf(__shfl(lsum, qrel), 1e-25f);
    }
#pragma unroll
    for (int reg = 0; reg < 16; ++reg) {
        const int qrow = qbase + wv * 32 + (reg & 3) + 8 * (reg >> 2) + 4 * hi;
        _Float16* op = out_f16 + ((size_t)(n * L_SEQ + qrow)) * EMB + h * HD;
        op[l32]      = (_Float16)(Ov[0][reg] * linv[reg]);
        op[32 + l32] = (_Float16)(Ov[1][reg] * linv[reg]);
    }
}

// ---------------------------------------------------------------------------
// FC: C[8192][1024] = A(f16) * W^T(f16) + bias. 128x128 tile, BK=64,
// global_load_lds staging (XOR-swizzled linear LDS), double-buffered,
// one barrier per K-step (m97-style structure).
// ---------------------------------------------------------------------------
__global__ __launch_bounds__(256) void fc_kernel(
    const _Float16* __restrict__ A, const _Float16* __restrict__ W,
    const float* __restrict__ bias, float* __restrict__ C)
{
    __shared__ __align__(16) _Float16 As[2][128 * 64];
    __shared__ __align__(16) _Float16 Ws[2][128 * 64];

    const int tid = threadIdx.x;
    const int lane = tid & 63;
    const int wv = tid >> 6;
    const int l16 = lane & 15;
    const int quad = lane >> 4;
    const int wm = (wv >> 1) * 64, wn = (wv & 1) * 64;
    const int Mb = blockIdx.x * 128, Nb = blockIdx.y * 128;
    const int xr = l16 & 7;

    auto stage = [&](int buf, int k0) {
#pragma unroll
        for (int s = 0; s < 4; ++s) {
            const int row = wv * 32 + s * 8 + (lane >> 3);
            const int sc = (lane & 7) ^ (row & 7);       // pre-swizzled source chunk
            async16(A + (size_t)(Mb + row) * EMB + k0 + sc * 8, &As[buf][(wv * 32 + s * 8) * 64]);
            async16(W + (size_t)(Nb + row) * EMB + k0 + sc * 8, &Ws[buf][(wv * 32 + s * 8) * 64]);
        }
    };

    f32x4 acc[4][4];
#pragma unroll
    for (int i = 0; i < 4; ++i)
#pragma unroll
        for (int j = 0; j < 4; ++j) acc[i][j] = (f32x4){0.f, 0.f, 0.f, 0.f};

    stage(0, 0);
    int cur = 0;
#pragma unroll 2
    for (int k0 = 0; k0 < EMB; k0 += 64) {
        __syncthreads();                                 // tile k0 landed; prior reads consumed
        if (k0 + 64 < EMB) stage(cur ^ 1, k0 + 64);      // DMA next K-tile overlaps compute

        half8 af[4][2], bf[4][2];
#pragma unroll
        for (int i = 0; i < 4; ++i)
#pragma unroll
            for (int kk = 0; kk < 2; ++kk) {
                const int ch = (((kk * 4 + quad) ^ xr)) * 8;
                af[i][kk] = *(const half8*)(&As[cur][(wm + i * 16 + l16) * 64 + ch]);
                bf[i][kk] = *(const half8*)(&Ws[cur][(wn + i * 16 + l16) * 64 + ch]);
            }
        __builtin_amdgcn_s_setprio(1);
#pragma unroll
        for (int i = 0; i < 4; ++i)
#pragma unroll
            for (int j = 0; j < 4; ++j)
#pragma unroll
                for (int kk = 0; kk < 2; ++kk)
                    acc[i][j] = __builtin_amdgcn_mfma_f32_16x16x32_f16(af[i][kk], bf[j][kk], acc[i][j], 0, 0, 0);
        __builtin_amdgcn_s_setprio(0);
        cur ^= 1;
    }

#pragma unroll
    for (int i = 0; i < 4; ++i) {
        const int m = Mb + wm + i * 16 + quad * 4;
#pragma unroll
        for (int j = 0; j < 4; ++j) {
            const int jc = Nb + wn + j * 16 + l16;
            const float b = bias[jc];
#pragma unroll
            for (int reg = 0; reg < 4; ++reg)
                C[(size_t)(m + reg) * EMB + jc] = acc[i][j][reg] + b;
        }
    }
}

// ---------------------------------------------------------------------------
extern "C" void kernel_launch(void* const* d_in, const int* in_sizes, int n_in,
                              void* d_out, int out_size, void* d_ws, size_t ws_size,
                              hipStream_t stream) {
    const float* values  = (const float*)d_in[0];
    const float* keys    = (const float*)d_in[1];
    const float* queries = (const float*)d_in[2];
    const float* fc_w    = (const float*)d_in[3];
    const float* fc_b    = (const float*)d_in[4];
    const int*   amask   = (const int*)d_in[5];
    const int*   pmask   = (const int*)d_in[6];
    float* out = (float*)d_out;

    // ws: [0,16M) attn_out f16 | [16M,18M) W f16 | [18M,+128K) mbits |
    //     [18M+128K,+1K) pbits | [19M,35M) K16 | [35M,51M) Vt16
    char* w = (char*)d_ws;
    _Float16* attn_out = (_Float16*)w;
    _Float16* w_f16    = (_Float16*)(w + (size_t)16 * 1024 * 1024);
    u32*      mbits    = (u32*)(w + (size_t)18 * 1024 * 1024);
    u32*      pbits    = (u32*)(w + (size_t)18 * 1024 * 1024 + 128 * 1024);
    _Float16* K16      = (_Float16*)(w + (size_t)19 * 1024 * 1024);
    _Float16* Vt16     = (_Float16*)(w + (size_t)35 * 1024 * 1024);

    prep_kernel<<<4096, 256, 0, stream>>>(amask, mbits, pmask, pbits, fc_w, w_f16);
    cvt_kv_kernel<<<dim3(16, 16, 8), 256, 0, stream>>>(keys, values, K16, Vt16);
    attn_kernel<<<1024, 256, 0, stream>>>(K16, Vt16, queries, mbits, pbits, attn_out);
    fc_kernel<<<dim3(64, 8), 256, 0, stream>>>(attn_out, w_f16, fc_b, out);
}

// Round 7
// 223.634 us; speedup vs baseline: 1.0366x; 1.0366x over previous
//
#include <hip/hip_runtime.h>

#define L_SEQ 1024
#define EMB 1024
#define NH 16
#define HD 64

typedef _Float16 half8 __attribute__((ext_vector_type(8)));
typedef _Float16 half4v __attribute__((ext_vector_type(4)));
typedef __fp16 h2 __attribute__((ext_vector_type(2)));
typedef float f32x4 __attribute__((ext_vector_type(4)));
typedef float f32x16 __attribute__((ext_vector_type(16)));
typedef float fvec4 __attribute__((ext_vector_type(4)));
typedef unsigned int u32;
typedef u32 u32x4 __attribute__((ext_vector_type(4)));
typedef unsigned long long u64;

constexpr float C2 = 0.045084220027780106f;   // SCALE * log2(e) -- folded into K16 prepass

constexpr int PP = 66;   // cvt_kv LDS pitch (132B rows: write banks 16-spread vs 8 @144B)

__device__ __forceinline__ void async16(const void* g, void* l) {
    __builtin_amdgcn_global_load_lds((const __attribute__((address_space(1))) u32*)g,
                                     (__attribute__((address_space(3))) u32*)l, 16, 0, 0);
}

// ---------------------------------------------------------------------------
// Prepass (merged): pack attn_mask bits; blocks<32 pack pad mask;
// blocks<1024 also convert fc_w fp32->f16. One launch instead of two.
// ---------------------------------------------------------------------------
__global__ void prep_kernel(const int* __restrict__ am, u32* __restrict__ bits,
                            const int* __restrict__ pad, u32* __restrict__ pbits,
                            const float* __restrict__ w, _Float16* __restrict__ o) {
    const int b = blockIdx.x;
    const int i = b * 256 + threadIdx.x;
    const int lane = threadIdx.x & 63;
    u64 bal = __ballot(am[i] != 0);
    if (lane == 0)       bits[i >> 5] = (u32)bal;
    else if (lane == 32) bits[i >> 5] = (u32)(bal >> 32);
    if (b < 32) {   // 8*1024 pad ints
        u64 pb = __ballot(pad[i] != 0);
        if (lane == 0)       pbits[i >> 5] = (u32)pb;
        else if (lane == 32) pbits[i >> 5] = (u32)(pb >> 32);
    }
    if (b < 1024) {   // fc_w convert: 1M floats
        size_t j = (size_t)i * 4;
        fvec4 v = *(const fvec4*)(w + j);
        half4v hh;
#pragma unroll
        for (int k = 0; k < 4; ++k) hh[k] = (_Float16)v[k];
        *(half4v*)(o + j) = hh;
    }
}

// ---------------------------------------------------------------------------
// Prepass: K -> f16 head-blocked (nh, k, d) scaled by C2; V -> f16 transposed
// ---------------------------------------------------------------------------
__global__ __launch_bounds__(256) void cvt_kv_kernel(
    const float* __restrict__ keys, const float* __restrict__ values,
    _Float16* __restrict__ K16, _Float16* __restrict__ Vt16)
{
    __shared__ __align__(16) _Float16 Vt[64 * PP];
    const int tid = threadIdx.x;
    const int kt = blockIdx.x, h = blockIdx.y, n = blockIdx.z;
    const int kbase = kt * 64;
    const int r = tid >> 2, c0 = (tid & 3) * 16;
    const int nh = n * NH + h;

    {   // K: reorder rows into head-blocked, convert, fold C2
        const float* src = keys + ((size_t)(n * L_SEQ + kbase + r)) * EMB + h * HD + c0;
        fvec4 a0 = *(const fvec4*)(src),     a1 = *(const fvec4*)(src + 4);
        fvec4 a2 = *(const fvec4*)(src + 8), a3 = *(const fvec4*)(src + 12);
        half8 o0, o1;
#pragma unroll
        for (int j = 0; j < 4; ++j) {
            o0[j] = (_Float16)(a0[j] * C2); o0[j + 4] = (_Float16)(a1[j] * C2);
            o1[j] = (_Float16)(a2[j] * C2); o1[j + 4] = (_Float16)(a3[j] * C2);
        }
        _Float16* dst = K16 + ((size_t)nh * L_SEQ + kbase + r) * HD + c0;
        *(half8*)dst = o0; *(half8*)(dst + 8) = o1;
    }
    {   // V: stage transposed tile in LDS (pitch 66: banks (c0+i)%32 + r/2)
        const float* src = values + ((size_t)(n * L_SEQ + kbase + r)) * EMB + h * HD + c0;
        fvec4 vv[4];
        vv[0] = *(const fvec4*)(src);     vv[1] = *(const fvec4*)(src + 4);
        vv[2] = *(const fvec4*)(src + 8); vv[3] = *(const fvec4*)(src + 12);
#pragma unroll
        for (int i = 0; i < 16; ++i)
            Vt[(c0 + i) * PP + r] = (_Float16)vv[i >> 2][i & 3];
    }
    __syncthreads();
    {   // write Vt16 rows (d-major); 132B rows are 4B-aligned -> u32 LDS reads
        const int d = tid >> 2, k0 = (tid & 3) * 16;
        const u32* vr = (const u32*)((const char*)Vt + (size_t)d * (PP * 2) + 2 * k0);
        u32 a[8];
#pragma unroll
        for (int m = 0; m < 8; ++m) a[m] = vr[m];
        u32x4 lo = {a[0], a[1], a[2], a[3]};
        u32x4 hi2 = {a[4], a[5], a[6], a[7]};
        _Float16* dst = Vt16 + ((size_t)nh * HD + d) * L_SEQ + kbase + k0;
        *(half8*)dst = __builtin_bit_cast(half8, lo);
        *(half8*)(dst + 8) = __builtin_bit_cast(half8, hi2);
    }
}

// ---------------------------------------------------------------------------
// Fused masked attention, S^T formulation on 32x32x16 MFMA, in-register
// softmax->PV (permlane32_swap). All in-loop VMEM loads are for tile kt+1
// (no mid-iteration vmcnt wait). ROUND-7: revert to (256,3) [(256,4) caused
// VGPR-64 spills: WRITE +12MB, dur +10us]; drop s_setprio (with 3 blocks/SIMD
// a prio-1 MFMA wave starves other blocks' softmax VALU -> kills cross-wave
// overlap, m190 mechanism).
// ---------------------------------------------------------------------------
__global__ __launch_bounds__(256, 3) void attn_kernel(
    const _Float16* __restrict__ K16, const _Float16* __restrict__ Vt16,
    const float* __restrict__ queries, const u32* __restrict__ mbits,
    const u32* __restrict__ pbits, _Float16* __restrict__ out_f16)
{
    __shared__ __align__(16) _Float16 K_lds[2][64 * 64];   // XOR-swizzled, double-buffered
    __shared__ __align__(16) _Float16 V_lds[2][64 * 64];   // V^T tile, XOR-swizzled, dbuf
    __shared__ __align__(8)  u32 mtab[32];                 // 4 mask bits -> packed f16 {0,1}x4

    const int tid  = threadIdx.x;
    const int lane = tid & 63;
    const int wv   = tid >> 6;
    const int l32  = lane & 31;
    const int hi   = lane >> 5;
    const int bid  = blockIdx.x;
    const int nh = bid & 127, qt = bid >> 7;
    const int n = nh >> 4, h = nh & 15;
    const int qbase = qt * 128;
    const int q = qbase + wv * 32 + l32;     // this lane's q (S^T column)
    const int rsw = l32 & 7;

    const _Float16* Kt_base = K16 + (size_t)nh * L_SEQ * HD;
    const _Float16* Vt_base = Vt16 + (size_t)nh * HD * L_SEQ;
    const int gch = (lane & 7) ^ ((lane >> 3) & 7);      // XOR-swizzled source chunk

    auto stage = [&](int buf, int kt) {
        const int kbase = kt * 64;
#pragma unroll
        for (int s2 = 0; s2 < 2; ++s2) {
            const int row = wv * 16 + s2 * 8 + (lane >> 3);
            async16(Kt_base + (size_t)(kbase + row) * HD + gch * 8,
                    &K_lds[buf][(wv * 16 + s2 * 8) * 64]);
            async16(Vt_base + (size_t)row * L_SEQ + kbase + gch * 8,
                    &V_lds[buf][(wv * 16 + s2 * 8) * 64]);
        }
    };

    // prologue: tile-0 masks + DMA issued before Q setup (drained by 1st barrier)
    uint2 wm_cur = *(const uint2*)(&mbits[(size_t)q * 32]);
    u32 pl_cur = pbits[n << 5];
    u32 ph_cur = pbits[(n << 5) + 1];
    stage(0, 0);

    if (tid < 16) {
        mtab[tid * 2]     = ((tid & 1) ? 0x3C00u : 0u) | ((tid & 2) ? 0x3C000000u : 0u);
        mtab[tid * 2 + 1] = ((tid & 4) ? 0x3C00u : 0u) | ((tid & 8) ? 0x3C000000u : 0u);
    }

    // --- Q fragments (B operand for S^T): lane holds Q[q][d = c*16 + hi*8 + j]
    half8 qf[4];
    {
        const float* qp = queries + ((size_t)(n * L_SEQ + q)) * EMB + h * HD;
#pragma unroll
        for (int c = 0; c < 4; ++c) {
            fvec4 a = *(const fvec4*)(qp + c * 16 + hi * 8);
            fvec4 b = *(const fvec4*)(qp + c * 16 + hi * 8 + 4);
#pragma unroll
            for (int j = 0; j < 4; ++j) { qf[c][j] = (_Float16)a[j]; qf[c][j + 4] = (_Float16)b[j]; }
        }
    }

    f32x16 Ov[2];
#pragma unroll
    for (int dt = 0; dt < 2; ++dt)
#pragma unroll
        for (int r = 0; r < 16; ++r) Ov[dt][r] = 0.f;
    float lsum = 0.f;
    const h2 one2 = {(__fp16)1.f, (__fp16)1.f};

    int cur = 0;
#pragma unroll 2
    for (int kt = 0; kt < L_SEQ / 64; ++kt) {
        __syncthreads();     // tile kt DMA + kt masks landed; prior-iter LDS reads consumed

        // issue tile kt+1 loads: masks FIRST, then DMA; nothing here is read
        // this iteration, so no vmcnt wait occurs inside the compute phase.
        uint2 wm_next = {0u, 0u};
        u32 pl_next = 0u, ph_next = 0u;
        if (kt + 1 < L_SEQ / 64) {
            wm_next = *(const uint2*)(&mbits[(size_t)q * 32 + (kt + 1) * 2]);
            pl_next = pbits[(n << 5) + ((kt + 1) << 1)];
            ph_next = pbits[(n << 5) + ((kt + 1) << 1) + 1];
            stage(cur ^ 1, kt + 1);
        }

        u32 w[2];
        w[0] = wm_cur.x & pl_cur;
        w[1] = wm_cur.y & ph_cur;

        // --- S^T = K * Q^T  (two 32x32 k-subtiles; C2 pre-folded into K16)
        f32x16 St[2];
#pragma unroll
        for (int i = 0; i < 2; ++i)
#pragma unroll
            for (int r = 0; r < 16; ++r) St[i][r] = 0.f;

        const _Float16* kb = &K_lds[cur][0];
#pragma unroll
        for (int c = 0; c < 4; ++c) {
            const int ch = ((2 * c + hi) ^ rsw) * 8;
            half8 kf0 = *(const half8*)(kb + l32 * 64 + ch);
            half8 kf1 = *(const half8*)(kb + (32 + l32) * 64 + ch);
            St[0] = __builtin_amdgcn_mfma_f32_32x32x16_f16(kf0, qf[c], St[0], 0, 0, 0);
            St[1] = __builtin_amdgcn_mfma_f32_32x32x16_f16(kf1, qf[c], St[1], 0, 0, 0);
        }

        // --- p = exp2(S) * m; pack to f16 pairs; permlane32_swap -> PV A-frags.
        //     St[i][reg] is k_rel = (reg&3)+8*(reg>>2)+4*hi (k = 32i + k_rel).
        u32 pa[4][4];   // [ks][word j' = 2*hi' + mp]
#pragma unroll
        for (int i = 0; i < 2; ++i) {
#pragma unroll
            for (int rgp = 0; rgp < 2; ++rgp) {
                const int rg_a = 2 * rgp, rg_b = 2 * rgp + 1;
                const u32 m4a = (w[i] >> (8 * rg_a + 4 * hi)) & 15u;
                const u32 m4b = (w[i] >> (8 * rg_b + 4 * hi)) & 15u;
                const uint2 mma = *(const uint2*)(&mtab[m4a * 2]);
                const uint2 mmb = *(const uint2*)(&mtab[m4b * 2]);
                const float pa0 = __builtin_amdgcn_exp2f(St[i][4 * rg_a + 0]);
                const float pa1 = __builtin_amdgcn_exp2f(St[i][4 * rg_a + 1]);
                const float pa2 = __builtin_amdgcn_exp2f(St[i][4 * rg_a + 2]);
                const float pa3 = __builtin_amdgcn_exp2f(St[i][4 * rg_a + 3]);
                const float pb0 = __builtin_amdgcn_exp2f(St[i][4 * rg_b + 0]);
                const float pb1 = __builtin_amdgcn_exp2f(St[i][4 * rg_b + 1]);
                const float pb2 = __builtin_amdgcn_exp2f(St[i][4 * rg_b + 2]);
                const float pb3 = __builtin_amdgcn_exp2f(St[i][4 * rg_b + 3]);
                const h2 a0 = __builtin_amdgcn_cvt_pkrtz(pa0, pa1) * __builtin_bit_cast(h2, mma.x);
                const h2 a1 = __builtin_amdgcn_cvt_pkrtz(pa2, pa3) * __builtin_bit_cast(h2, mma.y);
                const h2 b0 = __builtin_amdgcn_cvt_pkrtz(pb0, pb1) * __builtin_bit_cast(h2, mmb.x);
                const h2 b1 = __builtin_amdgcn_cvt_pkrtz(pb2, pb3) * __builtin_bit_cast(h2, mmb.y);
                lsum = __builtin_amdgcn_fdot2(a0, one2, lsum, false);
                lsum = __builtin_amdgcn_fdot2(a1, one2, lsum, false);
                lsum = __builtin_amdgcn_fdot2(b0, one2, lsum, false);
                lsum = __builtin_amdgcn_fdot2(b1, one2, lsum, false);
                u32 A0 = __builtin_bit_cast(u32, a0), A1 = __builtin_bit_cast(u32, a1);
                u32 B0 = __builtin_bit_cast(u32, b0), B1 = __builtin_bit_cast(u32, b1);
                // after swap: A' = {A.lo, B.lo} (j'=mp), B' = {A.hi, B.hi} (j'=2+mp)
                asm("v_permlane32_swap_b32 %0, %1" : "+v"(A0), "+v"(B0));
                asm("v_permlane32_swap_b32 %0, %1" : "+v"(A1), "+v"(B1));
                const int ks = i * 2 + rgp;
                pa[ks][0] = A0; pa[ks][1] = A1; pa[ks][2] = B0; pa[ks][3] = B1;
            }
        }

        // --- O += P * V  (A = P frag from swaps, B = V^T rows)
        const _Float16* vb = &V_lds[cur][0];
#pragma unroll
        for (int ks = 0; ks < 4; ++ks) {
            u32x4 pw = {pa[ks][0], pa[ks][1], pa[ks][2], pa[ks][3]};
            half8 pB = __builtin_bit_cast(half8, pw);
            const int ch = ((2 * ks + hi) ^ rsw) * 8;
            half8 vf0 = *(const half8*)(vb + l32 * 64 + ch);
            half8 vf1 = *(const half8*)(vb + (32 + l32) * 64 + ch);
            Ov[0] = __builtin_amdgcn_mfma_f32_32x32x16_f16(pB, vf0, Ov[0], 0, 0, 0);
            Ov[1] = __builtin_amdgcn_mfma_f32_32x32x16_f16(pB, vf1, Ov[1], 0, 0, 0);
        }

        wm_cur = wm_next; pl_cur = pl_next; ph_cur = ph_next;
        cur ^= 1;
    }

    // --- epilogue: complete row sums (lanes l, l^32 hold same q), normalize, store
    lsum += __shfl_xor(lsum, 32);
    float linv[16];
#pragma unroll
    for (int reg = 0; reg < 16; ++reg) {
        const int qrel = (reg & 3) + 8 * (reg >> 2) + 4 * hi;
        linv[reg] = 1.0f / fmaxf(__shfl(lsum, qrel), 1e-25f);
    }
#pragma unroll
    for (int reg = 0; reg < 16; ++reg) {
        const int qrow = qbase + wv * 32 + (reg & 3) + 8 * (reg >> 2) + 4 * hi;
        _Float16* op = out_f16 + ((size_t)(n * L_SEQ + qrow)) * EMB + h * HD;
        op[l32]      = (_Float16)(Ov[0][reg] * linv[reg]);
        op[32 + l32] = (_Float16)(Ov[1][reg] * linv[reg]);
    }
}

// ---------------------------------------------------------------------------
// FC: C[8192][1024] = A(f16) * W^T(f16) + bias. 128x128 tile, BK=64,
// global_load_lds staging (XOR-swizzled linear LDS), double-buffered,
// one barrier per K-step (m97-style structure). No setprio (lockstep waves).
// ---------------------------------------------------------------------------
__global__ __launch_bounds__(256) void fc_kernel(
    const _Float16* __restrict__ A, const _Float16* __restrict__ W,
    const float* __restrict__ bias, float* __restrict__ C)
{
    __shared__ __align__(16) _Float16 As[2][128 * 64];
    __shared__ __align__(16) _Float16 Ws[2][128 * 64];

    const int tid = threadIdx.x;
    const int lane = tid & 63;
    const int wv = tid >> 6;
    const int l16 = lane & 15;
    const int quad = lane >> 4;
    const int wm = (wv >> 1) * 64, wn = (wv & 1) * 64;
    const int Mb = blockIdx.x * 128, Nb = blockIdx.y * 128;
    const int xr = l16 & 7;

    auto stage = [&](int buf, int k0) {
#pragma unroll
        for (int s = 0; s < 4; ++s) {
            const int row = wv * 32 + s * 8 + (lane >> 3);
            const int sc = (lane & 7) ^ (row & 7);       // pre-swizzled source chunk
            async16(A + (size_t)(Mb + row) * EMB + k0 + sc * 8, &As[buf][(wv * 32 + s * 8) * 64]);
            async16(W + (size_t)(Nb + row) * EMB + k0 + sc * 8, &Ws[buf][(wv * 32 + s * 8) * 64]);
        }
    };

    f32x4 acc[4][4];
#pragma unroll
    for (int i = 0; i < 4; ++i)
#pragma unroll
        for (int j = 0; j < 4; ++j) acc[i][j] = (f32x4){0.f, 0.f, 0.f, 0.f};

    stage(0, 0);
    int cur = 0;
#pragma unroll 2
    for (int k0 = 0; k0 < EMB; k0 += 64) {
        __syncthreads();                                 // tile k0 landed; prior reads consumed
        if (k0 + 64 < EMB) stage(cur ^ 1, k0 + 64);      // DMA next K-tile overlaps compute

        half8 af[4][2], bf[4][2];
#pragma unroll
        for (int i = 0; i < 4; ++i)
#pragma unroll
            for (int kk = 0; kk < 2; ++kk) {
                const int ch = (((kk * 4 + quad) ^ xr)) * 8;
                af[i][kk] = *(const half8*)(&As[cur][(wm + i * 16 + l16) * 64 + ch]);
                bf[i][kk] = *(const half8*)(&Ws[cur][(wn + i * 16 + l16) * 64 + ch]);
            }
#pragma unroll
        for (int i = 0; i < 4; ++i)
#pragma unroll
            for (int j = 0; j < 4; ++j)
#pragma unroll
                for (int kk = 0; kk < 2; ++kk)
                    acc[i][j] = __builtin_amdgcn_mfma_f32_16x16x32_f16(af[i][kk], bf[j][kk], acc[i][j], 0, 0, 0);
        cur ^= 1;
    }

#pragma unroll
    for (int i = 0; i < 4; ++i) {
        const int m = Mb + wm + i * 16 + quad * 4;
#pragma unroll
        for (int j = 0; j < 4; ++j) {
            const int jc = Nb + wn + j * 16 + l16;
            const float b = bias[jc];
#pragma unroll
            for (int reg = 0; reg < 4; ++reg)
                C[(size_t)(m + reg) * EMB + jc] = acc[i][j][reg] + b;
        }
    }
}

// ---------------------------------------------------------------------------
extern "C" void kernel_launch(void* const* d_in, const int* in_sizes, int n_in,
                              void* d_out, int out_size, void* d_ws, size_t ws_size,
                              hipStream_t stream) {
    const float* values  = (const float*)d_in[0];
    const float* keys    = (const float*)d_in[1];
    const float* queries = (const float*)d_in[2];
    const float* fc_w    = (const float*)d_in[3];
    const float* fc_b    = (const float*)d_in[4];
    const int*   amask   = (const int*)d_in[5];
    const int*   pmask   = (const int*)d_in[6];
    float* out = (float*)d_out;

    // ws: [0,16M) attn_out f16 | [16M,18M) W f16 | [18M,+128K) mbits |
    //     [18M+128K,+1K) pbits | [19M,35M) K16 | [35M,51M) Vt16
    char* w = (char*)d_ws;
    _Float16* attn_out = (_Float16*)w;
    _Float16* w_f16    = (_Float16*)(w + (size_t)16 * 1024 * 1024);
    u32*      mbits    = (u32*)(w + (size_t)18 * 1024 * 1024);
    u32*      pbits    = (u32*)(w + (size_t)18 * 1024 * 1024 + 128 * 1024);
    _Float16* K16      = (_Float16*)(w + (size_t)19 * 1024 * 1024);
    _Float16* Vt16     = (_Float16*)(w + (size_t)35 * 1024 * 1024);

    prep_kernel<<<4096, 256, 0, stream>>>(amask, mbits, pmask, pbits, fc_w, w_f16);
    cvt_kv_kernel<<<dim3(16, 16, 8), 256, 0, stream>>>(keys, values, K16, Vt16);
    attn_kernel<<<1024, 256, 0, stream>>>(K16, Vt16, queries, mbits, pbits, attn_out);
    fc_kernel<<<dim3(64, 8), 256, 0, stream>>>(attn_out, w_f16, fc_b, out);
}

// Round 9
// 223.012 us; speedup vs baseline: 1.0395x; 1.0028x over previous
//
#include <hip/hip_runtime.h>

#define L_SEQ 1024
#define EMB 1024
#define NH 16
#define HD 64

typedef _Float16 half8 __attribute__((ext_vector_type(8)));
typedef _Float16 half4v __attribute__((ext_vector_type(4)));
typedef __fp16 h2 __attribute__((ext_vector_type(2)));
typedef float f32x4 __attribute__((ext_vector_type(4)));
typedef float f32x16 __attribute__((ext_vector_type(16)));
typedef float fvec4 __attribute__((ext_vector_type(4)));
typedef unsigned int u32;
typedef u32 u32x4 __attribute__((ext_vector_type(4)));
typedef unsigned long long u64;

constexpr float C2 = 0.045084220027780106f;   // SCALE * log2(e) -- folded into K16 prepass

constexpr int PP = 66;   // cvt_kv LDS pitch

__device__ __forceinline__ void async16(const void* g, void* l) {
    __builtin_amdgcn_global_load_lds((const __attribute__((address_space(1))) u32*)g,
                                     (__attribute__((address_space(3))) u32*)l, 16, 0, 0);
}

// ---------------------------------------------------------------------------
// Prepass (merged): pack attn_mask bits; blocks<32 pack pad mask;
// blocks<1024 also convert fc_w fp32->f16.
// ---------------------------------------------------------------------------
__global__ void prep_kernel(const int* __restrict__ am, u32* __restrict__ bits,
                            const int* __restrict__ pad, u32* __restrict__ pbits,
                            const float* __restrict__ w, _Float16* __restrict__ o) {
    const int b = blockIdx.x;
    const int i = b * 256 + threadIdx.x;
    const int lane = threadIdx.x & 63;
    u64 bal = __ballot(am[i] != 0);
    if (lane == 0)       bits[i >> 5] = (u32)bal;
    else if (lane == 32) bits[i >> 5] = (u32)(bal >> 32);
    if (b < 32) {
        u64 pb = __ballot(pad[i] != 0);
        if (lane == 0)       pbits[i >> 5] = (u32)pb;
        else if (lane == 32) pbits[i >> 5] = (u32)(pb >> 32);
    }
    if (b < 1024) {
        size_t j = (size_t)i * 4;
        fvec4 v = *(const fvec4*)(w + j);
        half4v hh;
#pragma unroll
        for (int k = 0; k < 4; ++k) hh[k] = (_Float16)v[k];
        *(half4v*)(o + j) = hh;
    }
}

// ---------------------------------------------------------------------------
// Prepass: K -> f16 head-blocked (nh, k, d) scaled by C2; V -> f16 transposed
// ---------------------------------------------------------------------------
__global__ __launch_bounds__(256) void cvt_kv_kernel(
    const float* __restrict__ keys, const float* __restrict__ values,
    _Float16* __restrict__ K16, _Float16* __restrict__ Vt16)
{
    __shared__ __align__(16) _Float16 Vt[64 * PP];
    const int tid = threadIdx.x;
    const int kt = blockIdx.x, h = blockIdx.y, n = blockIdx.z;
    const int kbase = kt * 64;
    const int r = tid >> 2, c0 = (tid & 3) * 16;
    const int nh = n * NH + h;

    {   // K: reorder rows into head-blocked, convert, fold C2
        const float* src = keys + ((size_t)(n * L_SEQ + kbase + r)) * EMB + h * HD + c0;
        fvec4 a0 = *(const fvec4*)(src),     a1 = *(const fvec4*)(src + 4);
        fvec4 a2 = *(const fvec4*)(src + 8), a3 = *(const fvec4*)(src + 12);
        half8 o0, o1;
#pragma unroll
        for (int j = 0; j < 4; ++j) {
            o0[j] = (_Float16)(a0[j] * C2); o0[j + 4] = (_Float16)(a1[j] * C2);
            o1[j] = (_Float16)(a2[j] * C2); o1[j + 4] = (_Float16)(a3[j] * C2);
        }
        _Float16* dst = K16 + ((size_t)nh * L_SEQ + kbase + r) * HD + c0;
        *(half8*)dst = o0; *(half8*)(dst + 8) = o1;
    }
    {   // V: stage transposed tile in LDS
        const float* src = values + ((size_t)(n * L_SEQ + kbase + r)) * EMB + h * HD + c0;
        fvec4 vv[4];
        vv[0] = *(const fvec4*)(src);     vv[1] = *(const fvec4*)(src + 4);
        vv[2] = *(const fvec4*)(src + 8); vv[3] = *(const fvec4*)(src + 12);
#pragma unroll
        for (int i = 0; i < 16; ++i)
            Vt[(c0 + i) * PP + r] = (_Float16)vv[i >> 2][i & 3];
    }
    __syncthreads();
    {   // write Vt16 rows (d-major); 132B rows are 4B-aligned -> u32 LDS reads
        const int d = tid >> 2, k0 = (tid & 3) * 16;
        const u32* vr = (const u32*)((const char*)Vt + (size_t)d * (PP * 2) + 2 * k0);
        u32 a[8];
#pragma unroll
        for (int m = 0; m < 8; ++m) a[m] = vr[m];
        u32x4 lo = {a[0], a[1], a[2], a[3]};
        u32x4 hi2 = {a[4], a[5], a[6], a[7]};
        _Float16* dst = Vt16 + ((size_t)nh * HD + d) * L_SEQ + kbase + k0;
        *(half8*)dst = __builtin_bit_cast(half8, lo);
        *(half8*)(dst + 8) = __builtin_bit_cast(half8, hi2);
    }
}

// ---------------------------------------------------------------------------
// Fused masked attention, S^T on 32x32x16 MFMA, in-register softmax->PV.
// 64 q per wave (2 q-fragments A,B). Each K/V LDS load feeds 2 MFMAs
// (1:2 read:MFMA); block = 256 q -> grid 512 = 2 blocks/CU exactly, zero
// tail; barriers, DMA instrs, K16/Vt16 rereads all halve per q.
// ---------------------------------------------------------------------------
__global__ __launch_bounds__(256, 2) void attn_kernel(
    const _Float16* __restrict__ K16, const _Float16* __restrict__ Vt16,
    const float* __restrict__ queries, const u32* __restrict__ mbits,
    const u32* __restrict__ pbits, _Float16* __restrict__ out_f16)
{
    __shared__ __align__(16) _Float16 K_lds[2][64 * 64];
    __shared__ __align__(16) _Float16 V_lds[2][64 * 64];
    __shared__ __align__(8)  u32 mtab[32];

    const int tid  = threadIdx.x;
    const int lane = tid & 63;
    const int wv   = tid >> 6;
    const int l32  = lane & 31;
    const int hi   = lane >> 5;
    const int bid  = blockIdx.x;
    const int nh = bid & 127, qt = bid >> 7;      // qt in 0..3
    const int n = nh >> 4, h = nh & 15;
    const int qbase = qt * 256;
    const int qA = qbase + wv * 64 + l32;         // frag A q; frag B = qA+32
    const int rsw = l32 & 7;

    const _Float16* Kt_base = K16 + (size_t)nh * L_SEQ * HD;
    const _Float16* Vt_base = Vt16 + (size_t)nh * HD * L_SEQ;
    const int gch = (lane & 7) ^ ((lane >> 3) & 7);

    auto stage = [&](int buf, int kt) {
        const int kbase = kt * 64;
#pragma unroll
        for (int s2 = 0; s2 < 2; ++s2) {
            const int row = wv * 16 + s2 * 8 + (lane >> 3);
            async16(Kt_base + (size_t)(kbase + row) * HD + gch * 8,
                    &K_lds[buf][(wv * 16 + s2 * 8) * 64]);
            async16(Vt_base + (size_t)row * L_SEQ + kbase + gch * 8,
                    &V_lds[buf][(wv * 16 + s2 * 8) * 64]);
        }
    };

    // prologue: tile-0 masks + DMA before Q setup (drained by 1st barrier)
    uint2 wmA = *(const uint2*)(&mbits[(size_t)qA * 32]);
    uint2 wmB = *(const uint2*)(&mbits[(size_t)(qA + 32) * 32]);
    u32 pl = pbits[n << 5];
    u32 ph = pbits[(n << 5) + 1];
    stage(0, 0);

    if (tid < 16) {
        mtab[tid * 2]     = ((tid & 1) ? 0x3C00u : 0u) | ((tid & 2) ? 0x3C000000u : 0u);
        mtab[tid * 2 + 1] = ((tid & 4) ? 0x3C00u : 0u) | ((tid & 8) ? 0x3C000000u : 0u);
    }

    // --- Q fragments for both halves
    half8 qfA[4], qfB[4];
    {
        const float* qpA = queries + ((size_t)(n * L_SEQ + qA)) * EMB + h * HD;
        const float* qpB = qpA + (size_t)32 * EMB;
#pragma unroll
        for (int c = 0; c < 4; ++c) {
            fvec4 a = *(const fvec4*)(qpA + c * 16 + hi * 8);
            fvec4 b = *(const fvec4*)(qpA + c * 16 + hi * 8 + 4);
            fvec4 e = *(const fvec4*)(qpB + c * 16 + hi * 8);
            fvec4 f = *(const fvec4*)(qpB + c * 16 + hi * 8 + 4);
#pragma unroll
            for (int j = 0; j < 4; ++j) {
                qfA[c][j] = (_Float16)a[j]; qfA[c][j + 4] = (_Float16)b[j];
                qfB[c][j] = (_Float16)e[j]; qfB[c][j + 4] = (_Float16)f[j];
            }
        }
    }

    f32x16 OvA0, OvA1, OvB0, OvB1;
#pragma unroll
    for (int r = 0; r < 16; ++r) { OvA0[r] = 0.f; OvA1[r] = 0.f; OvB0[r] = 0.f; OvB1[r] = 0.f; }
    float lsA = 0.f, lsB = 0.f;
    const h2 one2 = {(__fp16)1.f, (__fp16)1.f};

    int cur = 0;
#pragma unroll 2
    for (int kt = 0; kt < L_SEQ / 64; ++kt) {
        __syncthreads();     // tile kt DMA + masks landed; prior-iter LDS reads consumed

        uint2 wmA_n = {0u, 0u}, wmB_n = {0u, 0u};
        u32 pl_n = 0u, ph_n = 0u;
        if (kt + 1 < L_SEQ / 64) {
            wmA_n = *(const uint2*)(&mbits[(size_t)qA * 32 + (kt + 1) * 2]);
            wmB_n = *(const uint2*)(&mbits[(size_t)(qA + 32) * 32 + (kt + 1) * 2]);
            pl_n = pbits[(n << 5) + ((kt + 1) << 1)];
            ph_n = pbits[(n << 5) + ((kt + 1) << 1) + 1];
            stage(cur ^ 1, kt + 1);
        }

        const u32 wA[2] = {wmA.x & pl, wmA.y & ph};
        const u32 wB[2] = {wmB.x & pl, wmB.y & ph};

        const _Float16* kb = &K_lds[cur][0];
        const _Float16* vb = &V_lds[cur][0];

#pragma unroll
        for (int i = 0; i < 2; ++i) {      // 32-k subtile
            f32x16 StA, StB;
#pragma unroll
            for (int r = 0; r < 16; ++r) { StA[r] = 0.f; StB[r] = 0.f; }
#pragma unroll
            for (int c = 0; c < 4; ++c) {
                const int ch = ((2 * c + hi) ^ rsw) * 8;
                half8 kf = *(const half8*)(kb + (i * 32 + l32) * 64 + ch);
                StA = __builtin_amdgcn_mfma_f32_32x32x16_f16(kf, qfA[c], StA, 0, 0, 0);
                StB = __builtin_amdgcn_mfma_f32_32x32x16_f16(kf, qfB[c], StB, 0, 0, 0);
            }

            u32 paA[2][4], paB[2][4];
#pragma unroll
            for (int rgp = 0; rgp < 2; ++rgp) {
                const int rg_a = 2 * rgp, rg_b = 2 * rgp + 1;
                const int sh_a = 8 * rg_a + 4 * hi, sh_b = 8 * rg_b + 4 * hi;
                {   // frag A
                    const u32 m4a = (wA[i] >> sh_a) & 15u;
                    const u32 m4b = (wA[i] >> sh_b) & 15u;
                    const uint2 mma = *(const uint2*)(&mtab[m4a * 2]);
                    const uint2 mmb = *(const uint2*)(&mtab[m4b * 2]);
                    const float p0 = __builtin_amdgcn_exp2f(StA[4 * rg_a + 0]);
                    const float p1 = __builtin_amdgcn_exp2f(StA[4 * rg_a + 1]);
                    const float p2 = __builtin_amdgcn_exp2f(StA[4 * rg_a + 2]);
                    const float p3 = __builtin_amdgcn_exp2f(StA[4 * rg_a + 3]);
                    const float p4 = __builtin_amdgcn_exp2f(StA[4 * rg_b + 0]);
                    const float p5 = __builtin_amdgcn_exp2f(StA[4 * rg_b + 1]);
                    const float p6 = __builtin_amdgcn_exp2f(StA[4 * rg_b + 2]);
                    const float p7 = __builtin_amdgcn_exp2f(StA[4 * rg_b + 3]);
                    const h2 a0 = __builtin_amdgcn_cvt_pkrtz(p0, p1) * __builtin_bit_cast(h2, mma.x);
                    const h2 a1 = __builtin_amdgcn_cvt_pkrtz(p2, p3) * __builtin_bit_cast(h2, mma.y);
                    const h2 b0 = __builtin_amdgcn_cvt_pkrtz(p4, p5) * __builtin_bit_cast(h2, mmb.x);
                    const h2 b1 = __builtin_amdgcn_cvt_pkrtz(p6, p7) * __builtin_bit_cast(h2, mmb.y);
                    lsA = __builtin_amdgcn_fdot2(a0, one2, lsA, false);
                    lsA = __builtin_amdgcn_fdot2(a1, one2, lsA, false);
                    lsA = __builtin_amdgcn_fdot2(b0, one2, lsA, false);
                    lsA = __builtin_amdgcn_fdot2(b1, one2, lsA, false);
                    u32 A0 = __builtin_bit_cast(u32, a0), A1 = __builtin_bit_cast(u32, a1);
                    u32 B0 = __builtin_bit_cast(u32, b0), B1 = __builtin_bit_cast(u32, b1);
                    asm("v_permlane32_swap_b32 %0, %1" : "+v"(A0), "+v"(B0));
                    asm("v_permlane32_swap_b32 %0, %1" : "+v"(A1), "+v"(B1));
                    paA[rgp][0] = A0; paA[rgp][1] = A1; paA[rgp][2] = B0; paA[rgp][3] = B1;
                }
                {   // frag B
                    const u32 m4a = (wB[i] >> sh_a) & 15u;
                    const u32 m4b = (wB[i] >> sh_b) & 15u;
                    const uint2 mma = *(const uint2*)(&mtab[m4a * 2]);
                    const uint2 mmb = *(const uint2*)(&mtab[m4b * 2]);
                    const float p0 = __builtin_amdgcn_exp2f(StB[4 * rg_a + 0]);
                    const float p1 = __builtin_amdgcn_exp2f(StB[4 * rg_a + 1]);
                    const float p2 = __builtin_amdgcn_exp2f(StB[4 * rg_a + 2]);
                    const float p3 = __builtin_amdgcn_exp2f(StB[4 * rg_a + 3]);
                    const float p4 = __builtin_amdgcn_exp2f(StB[4 * rg_b + 0]);
                    const float p5 = __builtin_amdgcn_exp2f(StB[4 * rg_b + 1]);
                    const float p6 = __builtin_amdgcn_exp2f(StB[4 * rg_b + 2]);
                    const float p7 = __builtin_amdgcn_exp2f(StB[4 * rg_b + 3]);
                    const h2 a0 = __builtin_amdgcn_cvt_pkrtz(p0, p1) * __builtin_bit_cast(h2, mma.x);
                    const h2 a1 = __builtin_amdgcn_cvt_pkrtz(p2, p3) * __builtin_bit_cast(h2, mma.y);
                    const h2 b0 = __builtin_amdgcn_cvt_pkrtz(p4, p5) * __builtin_bit_cast(h2, mmb.x);
                    const h2 b1 = __builtin_amdgcn_cvt_pkrtz(p6, p7) * __builtin_bit_cast(h2, mmb.y);
                    lsB = __builtin_amdgcn_fdot2(a0, one2, lsB, false);
                    lsB = __builtin_amdgcn_fdot2(a1, one2, lsB, false);
                    lsB = __builtin_amdgcn_fdot2(b0, one2, lsB, false);
                    lsB = __builtin_amdgcn_fdot2(b1, one2, lsB, false);
                    u32 A0 = __builtin_bit_cast(u32, a0), A1 = __builtin_bit_cast(u32, a1);
                    u32 B0 = __builtin_bit_cast(u32, b0), B1 = __builtin_bit_cast(u32, b1);
                    asm("v_permlane32_swap_b32 %0, %1" : "+v"(A0), "+v"(B0));
                    asm("v_permlane32_swap_b32 %0, %1" : "+v"(A1), "+v"(B1));
                    paB[rgp][0] = A0; paB[rgp][1] = A1; paB[rgp][2] = B0; paB[rgp][3] = B1;
                }
            }

            // --- PV for this subtile's two 16-k groups (each V load feeds 2 MFMAs)
#pragma unroll
            for (int rgp = 0; rgp < 2; ++rgp) {
                const int ks = i * 2 + rgp;
                const int ch = ((2 * ks + hi) ^ rsw) * 8;
                half8 vf0 = *(const half8*)(vb + l32 * 64 + ch);
                half8 vf1 = *(const half8*)(vb + (32 + l32) * 64 + ch);
                u32x4 pwA = {paA[rgp][0], paA[rgp][1], paA[rgp][2], paA[rgp][3]};
                u32x4 pwB = {paB[rgp][0], paB[rgp][1], paB[rgp][2], paB[rgp][3]};
                half8 pA = __builtin_bit_cast(half8, pwA);
                half8 pB = __builtin_bit_cast(half8, pwB);
                OvA0 = __builtin_amdgcn_mfma_f32_32x32x16_f16(pA, vf0, OvA0, 0, 0, 0);
                OvA1 = __builtin_amdgcn_mfma_f32_32x32x16_f16(pA, vf1, OvA1, 0, 0, 0);
                OvB0 = __builtin_amdgcn_mfma_f32_32x32x16_f16(pB, vf0, OvB0, 0, 0, 0);
                OvB1 = __builtin_amdgcn_mfma_f32_32x32x16_f16(pB, vf1, OvB1, 0, 0, 0);
            }
        }

        wmA = wmA_n; wmB = wmB_n; pl = pl_n; ph = ph_n;
        cur ^= 1;
    }

    // --- epilogue: complete row sums, normalize, store both fragments
    lsA += __shfl_xor(lsA, 32);
    lsB += __shfl_xor(lsB, 32);
#pragma unroll
    for (int reg = 0; reg < 16; ++reg) {
        const int qrel = (reg & 3) + 8 * (reg >> 2) + 4 * hi;
        const float liA = 1.0f / fmaxf(__shfl(lsA, qrel), 1e-25f);
        const float liB = 1.0f / fmaxf(__shfl(lsB, qrel), 1e-25f);
        const int qrowA = qbase + wv * 64 + qrel;
        _Float16* opA = out_f16 + ((size_t)(n * L_SEQ + qrowA)) * EMB + h * HD;
        _Float16* opB = opA + (size_t)32 * EMB;
        opA[l32]      = (_Float16)(OvA0[reg] * liA);
        opA[32 + l32] = (_Float16)(OvA1[reg] * liA);
        opB[l32]      = (_Float16)(OvB0[reg] * liB);
        opB[32 + l32] = (_Float16)(OvB1[reg] * liB);
    }
}

// ---------------------------------------------------------------------------
// FC: C[8192][1024] = A(f16) * W^T(f16) + bias. 128x128 tile, BK=64,
// global_load_lds staging (XOR-swizzled linear LDS), double-buffered.
// ---------------------------------------------------------------------------
__global__ __launch_bounds__(256) void fc_kernel(
    const _Float16* __restrict__ A, const _Float16* __restrict__ W,
    const float* __restrict__ bias, float* __restrict__ C)
{
    __shared__ __align__(16) _Float16 As[2][128 * 64];
    __shared__ __align__(16) _Float16 Ws[2][128 * 64];

    const int tid = threadIdx.x;
    const int lane = tid & 63;
    const int wv = tid >> 6;
    const int l16 = lane & 15;
    const int quad = lane >> 4;
    const int wm = (wv >> 1) * 64, wn = (wv & 1) * 64;
    const int Mb = blockIdx.x * 128, Nb = blockIdx.y * 128;
    const int xr = l16 & 7;

    auto stage = [&](int buf, int k0) {
#pragma unroll
        for (int s = 0; s < 4; ++s) {
            const int row = wv * 32 + s * 8 + (lane >> 3);
            const int sc = (lane & 7) ^ (row & 7);
            async16(A + (size_t)(Mb + row) * EMB + k0 + sc * 8, &As[buf][(wv * 32 + s * 8) * 64]);
            async16(W + (size_t)(Nb + row) * EMB + k0 + sc * 8, &Ws[buf][(wv * 32 + s * 8) * 64]);
        }
    };

    f32x4 acc[4][4];
#pragma unroll
    for (int i = 0; i < 4; ++i)
#pragma unroll
        for (int j = 0; j < 4; ++j) acc[i][j] = (f32x4){0.f, 0.f, 0.f, 0.f};

    stage(0, 0);
    int cur = 0;
#pragma unroll 2
    for (int k0 = 0; k0 < EMB; k0 += 64) {
        __syncthreads();
        if (k0 + 64 < EMB) stage(cur ^ 1, k0 + 64);

        half8 af[4][2], bf[4][2];
#pragma unroll
        for (int i = 0; i < 4; ++i)
#pragma unroll
            for (int kk = 0; kk < 2; ++kk) {
                const int ch = (((kk * 4 + quad) ^ xr)) * 8;
                af[i][kk] = *(const half8*)(&As[cur][(wm + i * 16 + l16) * 64 + ch]);
                bf[i][kk] = *(const half8*)(&Ws[cur][(wn + i * 16 + l16) * 64 + ch]);
            }
#pragma unroll
        for (int i = 0; i < 4; ++i)
#pragma unroll
            for (int j = 0; j < 4; ++j)
#pragma unroll
                for (int kk = 0; kk < 2; ++kk)
                    acc[i][j] = __builtin_amdgcn_mfma_f32_16x16x32_f16(af[i][kk], bf[j][kk], acc[i][j], 0, 0, 0);
        cur ^= 1;
    }

#pragma unroll
    for (int i = 0; i < 4; ++i) {
        const int m = Mb + wm + i * 16 + quad * 4;
#pragma unroll
        for (int j = 0; j < 4; ++j) {
            const int jc = Nb + wn + j * 16 + l16;
            const float b = bias[jc];
#pragma unroll
            for (int reg = 0; reg < 4; ++reg)
                C[(size_t)(m + reg) * EMB + jc] = acc[i][j][reg] + b;
        }
    }
}

// ---------------------------------------------------------------------------
extern "C" void kernel_launch(void* const* d_in, const int* in_sizes, int n_in,
                              void* d_out, int out_size, void* d_ws, size_t ws_size,
                              hipStream_t stream) {
    const float* values  = (const float*)d_in[0];
    const float* keys    = (const float*)d_in[1];
    const float* queries = (const float*)d_in[2];
    const float* fc_w    = (const float*)d_in[3];
    const float* fc_b    = (const float*)d_in[4];
    const int*   amask   = (const int*)d_in[5];
    const int*   pmask   = (const int*)d_in[6];
    float* out = (float*)d_out;

    char* w = (char*)d_ws;
    _Float16* attn_out = (_Float16*)w;
    _Float16* w_f16    = (_Float16*)(w + (size_t)16 * 1024 * 1024);
    u32*      mbits    = (u32*)(w + (size_t)18 * 1024 * 1024);
    u32*      pbits    = (u32*)(w + (size_t)18 * 1024 * 1024 + 128 * 1024);
    _Float16* K16      = (_Float16*)(w + (size_t)19 * 1024 * 1024);
    _Float16* Vt16     = (_Float16*)(w + (size_t)35 * 1024 * 1024);

    prep_kernel<<<4096, 256, 0, stream>>>(amask, mbits, pmask, pbits, fc_w, w_f16);
    cvt_kv_kernel<<<dim3(16, 16, 8), 256, 0, stream>>>(keys, values, K16, Vt16);
    attn_kernel<<<512, 256, 0, stream>>>(K16, Vt16, queries, mbits, pbits, attn_out);
    fc_kernel<<<dim3(64, 8), 256, 0, stream>>>(attn_out, w_f16, fc_b, out);
}